// Round 4
// baseline (220.925 us; speedup 1.0000x reference)
//
#include <hip/hip_runtime.h>
#include <hip/hip_bf16.h>

#define DFEAT 64
#define NBSH  8        // bucket = dst >> 8 (256 nodes per bucket)
#define NPB   256
#define EPB   2048     // edges per partition block (586 blocks -> 2.3/CU)
#define EPT   (EPB / 256)
#define CAPB  3584     // per-bucket edge capacity (mean 3070 + ~9 sigma)
#define REGS  4608     // per-bucket region stride: CAPB + 4*NPB pad slots

// ---- K1: one-pass bucket partition + global degree histogram ----
// LDS bucket hist -> one global atomicAdd per non-empty bucket to reserve a
// contiguous run -> LDS-cursor scatter of packed (dst&255)<<17|src.
// Also bumps deg[dst] (fire-and-forget atomic) so xsprep/CSR need no 2nd pass.
__global__ __launch_bounds__(256) void part_kernel(const int* __restrict__ ei,
                                                   int* __restrict__ deg,
                                                   int* __restrict__ bcnt,
                                                   unsigned* __restrict__ ebuf, int E) {
    __shared__ int h[512];
    __shared__ int base[512];
    int t = threadIdx.x;
    h[t] = 0; h[t + 256] = 0;
    __syncthreads();
    int bb = blockIdx.x * EPB;
    int sv[EPT], dv[EPT];
    #pragma unroll
    for (int i = 0; i < EPT; ++i) {
        int e = bb + i * 256 + t;
        if (e < E) {
            sv[i] = ei[e];
            dv[i] = ei[E + e];
            atomicAdd(&h[dv[i] >> NBSH], 1);
            atomicAdd(&deg[dv[i]], 1);          // no return -> throughput-bound
        } else dv[i] = -1;
    }
    __syncthreads();
    base[t]       = h[t]       ? atomicAdd(&bcnt[t],       h[t])       : 0;
    base[t + 256] = h[t + 256] ? atomicAdd(&bcnt[t + 256], h[t + 256]) : 0;
    __syncthreads();
    h[t] = 0; h[t + 256] = 0;
    __syncthreads();
    #pragma unroll
    for (int i = 0; i < EPT; ++i) {
        if (dv[i] >= 0) {
            int bkt = dv[i] >> NBSH;
            int pos = base[bkt] + atomicAdd(&h[bkt], 1);
            if (pos < CAPB)
                ebuf[(size_t)bkt * REGS + pos] =
                    (unsigned)sv[i] | ((unsigned)(dv[i] & (NPB - 1)) << 17);
        }
    }
}

// ---- K2 (fused): blocks < nbuck build per-bucket CSR in place;
//      blocks >= nbuck do fully-parallel xs prep (+dinv).
// CSR path: deg already known (no hist pass); uint4-staged LDS copy; scan;
// [self][edges][sentinels pad x4] written over the same region.
__global__ __launch_bounds__(256) void prep_kernel(const int* __restrict__ deg,
                                                   const int* __restrict__ bcnt,
                                                   unsigned* __restrict__ buf,
                                                   int* __restrict__ begs,
                                                   int* __restrict__ lens,
                                                   float* __restrict__ dinv,
                                                   const float* __restrict__ x,
                                                   unsigned* __restrict__ xs,
                                                   int n, int nbuck) {
    __shared__ unsigned eb[CAPB];   // 14 KB
    __shared__ int tmp[256];
    __shared__ int cnt[256];
    int t = threadIdx.x;

    if ((int)blockIdx.x >= nbuck) {
        // ---- xs prep: BW-bound, fat grid ----
        int i = ((int)blockIdx.x - nbuck) * 256 + t;
        int total = (n + 1) * 32;
        if (i >= total) return;
        int row = i >> 5, col = i & 31;
        unsigned v = 0;
        if (row < n) {
            float di = rsqrtf((float)(deg[row] + 1));
            if (col == 0) dinv[row] = di;
            float f0 = x[(size_t)row * DFEAT + 2 * col] * di;
            float f1 = x[(size_t)row * DFEAT + 2 * col + 1] * di;
            unsigned u0 = __float_as_uint(f0); u0 = (u0 + 0x7fffu + ((u0 >> 16) & 1u)) >> 16;
            unsigned u1 = __float_as_uint(f1); u1 = (u1 + 0x7fffu + ((u1 >> 16) & 1u)) >> 16;
            v = (u0 & 0xffffu) | (u1 << 16);
        }
        xs[i] = v;
        return;
    }

    // ---- bucket CSR build ----
    int b = blockIdx.x;
    size_t rb = (size_t)b * REGS;
    int ecnt = bcnt[b]; if (ecnt > CAPB) ecnt = CAPB;

    // stage packed edges to LDS, 16B vectors (region is 16B-aligned)
    const uint4* bufv = (const uint4*)(buf + rb);
    uint4* ebv = (uint4*)eb;
    int nv = (ecnt + 3) >> 2;
    for (int i = t; i < nv; i += 256) ebv[i] = bufv[i];

    int nid = (b << NBSH) + t;
    int d = (nid < n) ? deg[nid] : 0;
    int slots = (nid < n) ? ((d + 4) & ~3) : 0;     // >= d+1, multiple of 4
    tmp[t] = slots;
    __syncthreads();                                 // also fences staging
    int s = slots;
    for (int o = 1; o < 256; o <<= 1) {
        int y = (t >= o) ? tmp[t - o] : 0;
        __syncthreads();
        tmp[t] += y;
        __syncthreads();
    }
    int excl = tmp[t] - s;
    int beg = (int)rb + excl;
    if (nid < n) {
        begs[nid] = beg;
        lens[nid] = slots;
        buf[beg] = (unsigned)nid;                              // self-loop
        for (int k = d + 1; k < slots; ++k) buf[beg + k] = (unsigned)n;  // sentinels
    }
    cnt[t] = excl + 1;                                         // cursor past self
    __syncthreads();
    for (int i = t; i < ecnt; i += 256) {
        unsigned v = eb[i];
        int pos = atomicAdd(&cnt[v >> 17], 1);
        buf[rb + pos] = v & 0x1ffffu;
    }
}

// ---- Persistent fused DUAL-NODE gather -> shared GEMM(+bias) -> expmap0 -> proj ----
// (UNCHANGED)
__global__ __launch_bounds__(256) void agg_kernel(const int* __restrict__ begs,
                                                  const int* __restrict__ lens,
                                                  const int* __restrict__ srcs,
                                                  const float* __restrict__ dinv,
                                                  const uint2* __restrict__ xs2,
                                                  const float* __restrict__ W,
                                                  const float* __restrict__ b,
                                                  float* __restrict__ out,
                                                  int n, int noctets) {
    __shared__ float Wl[DFEAT * DFEAT];   // 16 KB
    __shared__ float xl[8][DFEAT];        // 2 KB
    int t = threadIdx.x;
    #pragma unroll
    for (int i = 0; i < 16; ++i) Wl[i * 256 + t] = W[i * 256 + t];
    __syncthreads();   // the ONLY barrier

    int r = t >> 6, lane = t & 63;
    int g = lane >> 4;        // edge group (0..3)
    int q = lane & 15;        // uint2 column -> features 4q..4q+3
    float bias = b[lane];

    for (int oct = blockIdx.x; oct < noctets; oct += gridDim.x) {
        int na = oct * 8 + r;
        int nb_ = na + 4;
        bool va = na < n, vb = nb_ < n;
        if (!va) continue;

        int beg0 = begs[na],  end0 = beg0 + lens[na];
        int beg1 = 0, end1 = 0;
        if (vb) { beg1 = begs[nb_]; end1 = beg1 + lens[nb_]; }

        float a0 = 0, a1 = 0, a2 = 0, a3 = 0;
        float b0 = 0, b1 = 0, b2 = 0, b3 = 0;
        int base0 = beg0, base1 = beg1;
        while (base0 < end0 || base1 < end1) {
            int m0 = end0 - base0; m0 = m0 < 0 ? 0 : (m0 > 64 ? 64 : m0);
            int m1 = end1 - base1; m1 = m1 < 0 ? 0 : (m1 > 64 ? 64 : m1);
            int idx0 = 0, idx1 = 0;
            if (lane < m0) idx0 = srcs[base0 + lane];
            if (lane < m1) idx1 = srcs[base1 + lane];
            int q0 = m0 >> 2, q1 = m1 >> 2;
            int qc = q0 < q1 ? q0 : q1;
            #pragma unroll 4
            for (int j = 0; j < qc; ++j) {
                int sv0 = __shfl(idx0, 4 * j + g, 64);
                int sv1 = __shfl(idx1, 4 * j + g, 64);
                uint2 d0 = xs2[(unsigned)sv0 * 16 + q];
                uint2 d1 = xs2[(unsigned)sv1 * 16 + q];
                a0 += __uint_as_float(d0.x << 16);
                a1 += __uint_as_float(d0.x & 0xffff0000u);
                a2 += __uint_as_float(d0.y << 16);
                a3 += __uint_as_float(d0.y & 0xffff0000u);
                b0 += __uint_as_float(d1.x << 16);
                b1 += __uint_as_float(d1.x & 0xffff0000u);
                b2 += __uint_as_float(d1.y << 16);
                b3 += __uint_as_float(d1.y & 0xffff0000u);
            }
            #pragma unroll 4
            for (int j = qc; j < q0; ++j) {
                int sv0 = __shfl(idx0, 4 * j + g, 64);
                uint2 d0 = xs2[(unsigned)sv0 * 16 + q];
                a0 += __uint_as_float(d0.x << 16);
                a1 += __uint_as_float(d0.x & 0xffff0000u);
                a2 += __uint_as_float(d0.y << 16);
                a3 += __uint_as_float(d0.y & 0xffff0000u);
            }
            #pragma unroll 4
            for (int j = qc; j < q1; ++j) {
                int sv1 = __shfl(idx1, 4 * j + g, 64);
                uint2 d1 = xs2[(unsigned)sv1 * 16 + q];
                b0 += __uint_as_float(d1.x << 16);
                b1 += __uint_as_float(d1.x & 0xffff0000u);
                b2 += __uint_as_float(d1.y << 16);
                b3 += __uint_as_float(d1.y & 0xffff0000u);
            }
            base0 += 64; base1 += 64;
        }
        #pragma unroll
        for (int off = 16; off < 64; off <<= 1) {
            a0 += __shfl_xor(a0, off, 64);
            a1 += __shfl_xor(a1, off, 64);
            a2 += __shfl_xor(a2, off, 64);
            a3 += __shfl_xor(a3, off, 64);
            b0 += __shfl_xor(b0, off, 64);
            b1 += __shfl_xor(b1, off, 64);
            b2 += __shfl_xor(b2, off, 64);
            b3 += __shfl_xor(b3, off, 64);
        }
        if (g == 0) {
            float dia = dinv[na];
            xl[r][4 * q + 0] = a0 * dia;
            xl[r][4 * q + 1] = a1 * dia;
            xl[r][4 * q + 2] = a2 * dia;
            xl[r][4 * q + 3] = a3 * dia;
            if (vb) {
                float dib = dinv[nb_];
                xl[r + 4][4 * q + 0] = b0 * dib;
                xl[r + 4][4 * q + 1] = b1 * dib;
                xl[r + 4][4 * q + 2] = b2 * dib;
                xl[r + 4][4 * q + 3] = b3 * dib;
            }
        }
        // wave-synchronous LDS: same wave wrote xl rows r / r+4, same wave reads.

        float oa0 = bias, oa1 = 0.0f, ob0 = bias, ob1 = 0.0f;
        #pragma unroll
        for (int k = 0; k < DFEAT; k += 2) {
            float w0 = Wl[k * DFEAT + lane];
            float w1 = Wl[(k + 1) * DFEAT + lane];
            oa0 = fmaf(xl[r][k],     w0, oa0);
            oa1 = fmaf(xl[r][k + 1], w1, oa1);
            ob0 = fmaf(xl[r + 4][k],     w0, ob0);
            ob1 = fmaf(xl[r + 4][k + 1], w1, ob1);
        }
        float oa = oa0 + oa1;
        float ob = ob0 + ob1;

        float ssa = oa * oa, ssb = ob * ob;
        #pragma unroll
        for (int off = 32; off > 0; off >>= 1) {
            ssa += __shfl_xor(ssa, off, 64);
            ssb += __shfl_xor(ssb, off, 64);
        }
        float norma = fmaxf(sqrtf(ssa), 1e-15f);
        float sca = fminf(tanhf(norma), 1.0f - 4e-3f) / norma;
        out[(long long)na * DFEAT + lane] = oa * sca;
        if (vb) {
            float normb = fmaxf(sqrtf(ssb), 1e-15f);
            float scb = fminf(tanhf(normb), 1.0f - 4e-3f) / normb;
            out[(long long)nb_ * DFEAT + lane] = ob * scb;
        }
    }
}

// ---------------- launch ----------------

extern "C" void kernel_launch(void* const* d_in, const int* in_sizes, int n_in,
                              void* d_out, int out_size, void* d_ws, size_t ws_size,
                              hipStream_t stream) {
    const float* x = (const float*)d_in[0];
    const float* W = (const float*)d_in[1];
    const float* b = (const float*)d_in[2];
    const int* ei  = (const int*)d_in[3];

    int n = in_sizes[0] / DFEAT;           // 100000
    int E = in_sizes[3] / 2;               // 1200000
    int NBUCK = (n + NPB - 1) / NPB;       // 391
    int nblk = (E + EPB - 1) / EPB;        // 586
    int noctets = (n + 7) / 8;             // 12500
    int np = (n + 3) & ~3;                 // pad for 16B alignment of buf

    // workspace layout, ~21.6 MB total
    int* deg  = (int*)d_ws;                               // np (zeroed)
    int* bcnt = deg + np;                                 // 512 (zeroed)
    unsigned* buf = (unsigned*)(bcnt + 512);              // NBUCK*REGS (~7.2 MB), 16B-aligned
    int* begs = (int*)(buf + (size_t)NBUCK * REGS);       // n
    int* lens = begs + n;                                 // n
    float* dinv = (float*)(lens + n);                     // n
    size_t xsoff = (size_t)(((int*)dinv + n) - (int*)d_ws);
    xsoff = (xsoff + 31) & ~(size_t)31;                   // 128B-align
    unsigned* xs = (unsigned*)d_ws + xsoff;               // (n+1)*32

    float* out = (float*)d_out;

    int aggblocks = 2048;                  // 8 blocks/CU (LDS 18K)
    if (aggblocks > noctets) aggblocks = noctets;
    int xsblocks = ((n + 1) * 32 + 255) / 256;            // 12501

    hipMemsetAsync(deg, 0, (size_t)(np + 512) * sizeof(int), stream);
    part_kernel<<<nblk, 256, 0, stream>>>(ei, deg, bcnt, buf, E);
    prep_kernel<<<NBUCK + xsblocks, 256, 0, stream>>>(deg, bcnt, buf, begs, lens,
                                                      dinv, x, xs, n, NBUCK);
    agg_kernel <<<aggblocks, 256, 0, stream>>>(begs, lens, (const int*)buf, dinv,
                                               (const uint2*)xs, W, b, out, n, noctets);
}

// Round 5
// 185.510 us; speedup vs baseline: 1.1909x; 1.1909x over previous
//
#include <hip/hip_runtime.h>
#include <hip/hip_bf16.h>

#define DFEAT 64
#define NBSH  8        // bucket = dst >> 8 (256 nodes per bucket)
#define NPB   256
#define EPB   2048     // edges per partition block (586 blocks -> 2.3/CU)
#define EPT   (EPB / 256)
#define CAPB  3584     // per-bucket edge capacity (mean 3070 + ~9 sigma)
#define REGS  4608     // per-bucket region stride: CAPB + 4*NPB pad slots

// ---- K1: one-pass bucket partition (NO per-node global atomics) ----
// LDS bucket hist -> one global atomicAdd per non-empty bucket to reserve a
// contiguous run -> LDS-cursor scatter of packed (dst&255)<<17|src.
__global__ __launch_bounds__(256) void part_kernel(const int* __restrict__ ei,
                                                   int* __restrict__ bcnt,
                                                   unsigned* __restrict__ ebuf, int E) {
    __shared__ int h[512];
    __shared__ int base[512];
    int t = threadIdx.x;
    h[t] = 0; h[t + 256] = 0;
    __syncthreads();
    int bb = blockIdx.x * EPB;
    int sv[EPT], dv[EPT];
    #pragma unroll
    for (int i = 0; i < EPT; ++i) {
        int e = bb + i * 256 + t;
        if (e < E) {
            sv[i] = ei[e];
            dv[i] = ei[E + e];
            atomicAdd(&h[dv[i] >> NBSH], 1);
        } else dv[i] = -1;
    }
    __syncthreads();
    base[t]       = h[t]       ? atomicAdd(&bcnt[t],       h[t])       : 0;
    base[t + 256] = h[t + 256] ? atomicAdd(&bcnt[t + 256], h[t + 256]) : 0;
    __syncthreads();
    h[t] = 0; h[t + 256] = 0;
    __syncthreads();
    #pragma unroll
    for (int i = 0; i < EPT; ++i) {
        if (dv[i] >= 0) {
            int bkt = dv[i] >> NBSH;
            int pos = base[bkt] + atomicAdd(&h[bkt], 1);
            if (pos < CAPB)
                ebuf[(size_t)bkt * REGS + pos] =
                    (unsigned)sv[i] | ((unsigned)(dv[i] & (NPB - 1)) << 17);
        }
    }
}

// ---- K2: per-bucket CSR build IN PLACE (LDS-staged, LDS deg hist) ----
// Stages the bucket's packed edges in LDS (uint4), LDS-histograms degrees,
// then rewrites the same global region as [self][edges][sentinels pad x4].
// Writes dinv. NO xs tail (that's a separate fat kernel).
__global__ __launch_bounds__(256) void csr_kernel(const int* __restrict__ bcnt,
                                                  unsigned* __restrict__ buf,
                                                  int* __restrict__ begs,
                                                  int* __restrict__ lens,
                                                  float* __restrict__ dinv, int n) {
    __shared__ unsigned eb[CAPB];   // 14 KB
    __shared__ int cnt[256];
    __shared__ int tmp[256];
    int t = threadIdx.x, b = blockIdx.x;
    int ecnt = bcnt[b]; if (ecnt > CAPB) ecnt = CAPB;
    size_t rb = (size_t)b * REGS;

    // stage packed edges to LDS, 16B vectors (region is 16B-aligned)
    const uint4* bufv = (const uint4*)(buf + rb);
    uint4* ebv = (uint4*)eb;
    int nv = (ecnt + 3) >> 2;
    for (int i = t; i < nv; i += 256) ebv[i] = bufv[i];
    cnt[t] = 0;
    __syncthreads();                                 // fences staging + cnt init
    for (int i = t; i < ecnt; i += 256) atomicAdd(&cnt[eb[i] >> 17], 1);
    __syncthreads();

    int nid = (b << NBSH) + t;
    int deg = cnt[t];
    int slots = (nid < n) ? ((deg + 4) & ~3) : 0;    // >= deg+1, multiple of 4
    tmp[t] = slots;
    __syncthreads();
    int s = slots;
    for (int o = 1; o < 256; o <<= 1) {
        int y = (t >= o) ? tmp[t - o] : 0;
        __syncthreads();
        tmp[t] += y;
        __syncthreads();
    }
    int excl = tmp[t] - s;
    int beg = (int)rb + excl;
    if (nid < n) {
        begs[nid] = beg;
        lens[nid] = slots;
        dinv[nid] = rsqrtf((float)(deg + 1));
        buf[beg] = (unsigned)nid;                              // self-loop
        for (int k = deg + 1; k < slots; ++k) buf[beg + k] = (unsigned)n;  // sentinels
    }
    cnt[t] = excl + 1;                                         // cursor past self
    __syncthreads();
    for (int i = t; i < ecnt; i += 256) {
        unsigned v = eb[i];
        int pos = atomicAdd(&cnt[v >> 17], 1);
        buf[rb + pos] = v & 0x1ffffu;
    }
}

// ---- K3: xs[row] = bf16(x[row] * dinv[row]) packed 2/dword; row n = zeros ----
// Fat grid (12501 blocks), pure BW.
__global__ __launch_bounds__(256) void xsprep_kernel(const float* __restrict__ x,
                                                     const float* __restrict__ dinv,
                                                     unsigned* __restrict__ xs, int n) {
    int i = blockIdx.x * blockDim.x + threadIdx.x;
    int total = (n + 1) * 32;
    if (i >= total) return;
    int row = i >> 5, col = i & 31;
    unsigned v = 0;
    if (row < n) {
        float di = dinv[row];
        float f0 = x[(size_t)row * DFEAT + 2 * col] * di;
        float f1 = x[(size_t)row * DFEAT + 2 * col + 1] * di;
        unsigned u0 = __float_as_uint(f0); u0 = (u0 + 0x7fffu + ((u0 >> 16) & 1u)) >> 16;
        unsigned u1 = __float_as_uint(f1); u1 = (u1 + 0x7fffu + ((u1 >> 16) & 1u)) >> 16;
        v = (u0 & 0xffffu) | (u1 << 16);
    }
    xs[i] = v;
}

// ---- Persistent fused DUAL-NODE gather -> shared GEMM(+bias) -> expmap0 -> proj ----
// (UNCHANGED)
__global__ __launch_bounds__(256) void agg_kernel(const int* __restrict__ begs,
                                                  const int* __restrict__ lens,
                                                  const int* __restrict__ srcs,
                                                  const float* __restrict__ dinv,
                                                  const uint2* __restrict__ xs2,
                                                  const float* __restrict__ W,
                                                  const float* __restrict__ b,
                                                  float* __restrict__ out,
                                                  int n, int noctets) {
    __shared__ float Wl[DFEAT * DFEAT];   // 16 KB
    __shared__ float xl[8][DFEAT];        // 2 KB
    int t = threadIdx.x;
    #pragma unroll
    for (int i = 0; i < 16; ++i) Wl[i * 256 + t] = W[i * 256 + t];
    __syncthreads();   // the ONLY barrier

    int r = t >> 6, lane = t & 63;
    int g = lane >> 4;        // edge group (0..3)
    int q = lane & 15;        // uint2 column -> features 4q..4q+3
    float bias = b[lane];

    for (int oct = blockIdx.x; oct < noctets; oct += gridDim.x) {
        int na = oct * 8 + r;
        int nb_ = na + 4;
        bool va = na < n, vb = nb_ < n;
        if (!va) continue;

        int beg0 = begs[na],  end0 = beg0 + lens[na];
        int beg1 = 0, end1 = 0;
        if (vb) { beg1 = begs[nb_]; end1 = beg1 + lens[nb_]; }

        float a0 = 0, a1 = 0, a2 = 0, a3 = 0;
        float b0 = 0, b1 = 0, b2 = 0, b3 = 0;
        int base0 = beg0, base1 = beg1;
        while (base0 < end0 || base1 < end1) {
            int m0 = end0 - base0; m0 = m0 < 0 ? 0 : (m0 > 64 ? 64 : m0);
            int m1 = end1 - base1; m1 = m1 < 0 ? 0 : (m1 > 64 ? 64 : m1);
            int idx0 = 0, idx1 = 0;
            if (lane < m0) idx0 = srcs[base0 + lane];
            if (lane < m1) idx1 = srcs[base1 + lane];
            int q0 = m0 >> 2, q1 = m1 >> 2;
            int qc = q0 < q1 ? q0 : q1;
            #pragma unroll 4
            for (int j = 0; j < qc; ++j) {
                int sv0 = __shfl(idx0, 4 * j + g, 64);
                int sv1 = __shfl(idx1, 4 * j + g, 64);
                uint2 d0 = xs2[(unsigned)sv0 * 16 + q];
                uint2 d1 = xs2[(unsigned)sv1 * 16 + q];
                a0 += __uint_as_float(d0.x << 16);
                a1 += __uint_as_float(d0.x & 0xffff0000u);
                a2 += __uint_as_float(d0.y << 16);
                a3 += __uint_as_float(d0.y & 0xffff0000u);
                b0 += __uint_as_float(d1.x << 16);
                b1 += __uint_as_float(d1.x & 0xffff0000u);
                b2 += __uint_as_float(d1.y << 16);
                b3 += __uint_as_float(d1.y & 0xffff0000u);
            }
            #pragma unroll 4
            for (int j = qc; j < q0; ++j) {
                int sv0 = __shfl(idx0, 4 * j + g, 64);
                uint2 d0 = xs2[(unsigned)sv0 * 16 + q];
                a0 += __uint_as_float(d0.x << 16);
                a1 += __uint_as_float(d0.x & 0xffff0000u);
                a2 += __uint_as_float(d0.y << 16);
                a3 += __uint_as_float(d0.y & 0xffff0000u);
            }
            #pragma unroll 4
            for (int j = qc; j < q1; ++j) {
                int sv1 = __shfl(idx1, 4 * j + g, 64);
                uint2 d1 = xs2[(unsigned)sv1 * 16 + q];
                b0 += __uint_as_float(d1.x << 16);
                b1 += __uint_as_float(d1.x & 0xffff0000u);
                b2 += __uint_as_float(d1.y << 16);
                b3 += __uint_as_float(d1.y & 0xffff0000u);
            }
            base0 += 64; base1 += 64;
        }
        #pragma unroll
        for (int off = 16; off < 64; off <<= 1) {
            a0 += __shfl_xor(a0, off, 64);
            a1 += __shfl_xor(a1, off, 64);
            a2 += __shfl_xor(a2, off, 64);
            a3 += __shfl_xor(a3, off, 64);
            b0 += __shfl_xor(b0, off, 64);
            b1 += __shfl_xor(b1, off, 64);
            b2 += __shfl_xor(b2, off, 64);
            b3 += __shfl_xor(b3, off, 64);
        }
        if (g == 0) {
            float dia = dinv[na];
            xl[r][4 * q + 0] = a0 * dia;
            xl[r][4 * q + 1] = a1 * dia;
            xl[r][4 * q + 2] = a2 * dia;
            xl[r][4 * q + 3] = a3 * dia;
            if (vb) {
                float dib = dinv[nb_];
                xl[r + 4][4 * q + 0] = b0 * dib;
                xl[r + 4][4 * q + 1] = b1 * dib;
                xl[r + 4][4 * q + 2] = b2 * dib;
                xl[r + 4][4 * q + 3] = b3 * dib;
            }
        }
        // wave-synchronous LDS: same wave wrote xl rows r / r+4, same wave reads.

        float oa0 = bias, oa1 = 0.0f, ob0 = bias, ob1 = 0.0f;
        #pragma unroll
        for (int k = 0; k < DFEAT; k += 2) {
            float w0 = Wl[k * DFEAT + lane];
            float w1 = Wl[(k + 1) * DFEAT + lane];
            oa0 = fmaf(xl[r][k],     w0, oa0);
            oa1 = fmaf(xl[r][k + 1], w1, oa1);
            ob0 = fmaf(xl[r + 4][k],     w0, ob0);
            ob1 = fmaf(xl[r + 4][k + 1], w1, ob1);
        }
        float oa = oa0 + oa1;
        float ob = ob0 + ob1;

        float ssa = oa * oa, ssb = ob * ob;
        #pragma unroll
        for (int off = 32; off > 0; off >>= 1) {
            ssa += __shfl_xor(ssa, off, 64);
            ssb += __shfl_xor(ssb, off, 64);
        }
        float norma = fmaxf(sqrtf(ssa), 1e-15f);
        float sca = fminf(tanhf(norma), 1.0f - 4e-3f) / norma;
        out[(long long)na * DFEAT + lane] = oa * sca;
        if (vb) {
            float normb = fmaxf(sqrtf(ssb), 1e-15f);
            float scb = fminf(tanhf(normb), 1.0f - 4e-3f) / normb;
            out[(long long)nb_ * DFEAT + lane] = ob * scb;
        }
    }
}

// ---------------- launch ----------------

extern "C" void kernel_launch(void* const* d_in, const int* in_sizes, int n_in,
                              void* d_out, int out_size, void* d_ws, size_t ws_size,
                              hipStream_t stream) {
    const float* x = (const float*)d_in[0];
    const float* W = (const float*)d_in[1];
    const float* b = (const float*)d_in[2];
    const int* ei  = (const int*)d_in[3];

    int n = in_sizes[0] / DFEAT;           // 100000
    int E = in_sizes[3] / 2;               // 1200000
    int NBUCK = (n + NPB - 1) / NPB;       // 391
    int nblk = (E + EPB - 1) / EPB;        // 586
    int noctets = (n + 7) / 8;             // 12500

    // workspace layout, ~21.2 MB total
    int* bcnt = (int*)d_ws;                               // 512 (zeroed)
    unsigned* buf = (unsigned*)(bcnt + 512);              // NBUCK*REGS (~7.2 MB), 16B-aligned
    int* begs = (int*)(buf + (size_t)NBUCK * REGS);       // n
    int* lens = begs + n;                                 // n
    float* dinv = (float*)(lens + n);                     // n
    size_t xsoff = (size_t)(((int*)dinv + n) - (int*)d_ws);
    xsoff = (xsoff + 31) & ~(size_t)31;                   // 128B-align
    unsigned* xs = (unsigned*)d_ws + xsoff;               // (n+1)*32

    float* out = (float*)d_out;

    int aggblocks = 2048;                  // 8 blocks/CU (LDS 18K)
    if (aggblocks > noctets) aggblocks = noctets;
    int xsblocks = ((n + 1) * 32 + 255) / 256;            // 12501

    hipMemsetAsync(bcnt, 0, 512 * sizeof(int), stream);
    part_kernel  <<<nblk, 256, 0, stream>>>(ei, bcnt, buf, E);
    csr_kernel   <<<NBUCK, 256, 0, stream>>>(bcnt, buf, begs, lens, dinv, n);
    xsprep_kernel<<<xsblocks, 256, 0, stream>>>(x, dinv, xs, n);
    agg_kernel   <<<aggblocks, 256, 0, stream>>>(begs, lens, (const int*)buf, dinv,
                                                 (const uint2*)xs, W, b, out, n, noctets);
}

// Round 6
// 182.345 us; speedup vs baseline: 1.2116x; 1.0174x over previous
//
#include <hip/hip_runtime.h>
#include <hip/hip_bf16.h>

#define DFEAT 64
#define NBSH  8        // bucket = dst >> 8 (256 nodes per bucket)
#define NPB   256
#define EPB   4096     // edges per partition block (293 blocks)
#define EPT   (EPB / 256)
#define CAPB  3584     // per-bucket edge capacity (mean 3070 + ~9 sigma)
#define REGS  4608     // per-bucket region stride: CAPB + 4*NPB pad slots
#define BSTR  32       // bcnt stride in ints: 1 counter per 128B line (anti-contention)

// ---- K1: one-pass bucket partition ----
// LDS bucket hist -> one global atomicAdd per non-empty bucket (PADDED
// counters: each on its own 128B line so slices RMW in parallel) -> LDS-cursor
// scatter of packed (dst&255)<<17|src.
__global__ __launch_bounds__(256) void part_kernel(const int* __restrict__ ei,
                                                   int* __restrict__ bcnt,
                                                   unsigned* __restrict__ ebuf, int E) {
    __shared__ int h[512];
    __shared__ int base[512];
    int t = threadIdx.x;
    h[t] = 0; h[t + 256] = 0;
    __syncthreads();
    int bb = blockIdx.x * EPB;
    int sv[EPT], dv[EPT];
    #pragma unroll
    for (int i = 0; i < EPT; ++i) {
        int e = bb + i * 256 + t;
        if (e < E) {
            sv[i] = ei[e];
            dv[i] = ei[E + e];
            atomicAdd(&h[dv[i] >> NBSH], 1);
        } else dv[i] = -1;
    }
    __syncthreads();
    base[t]       = h[t]       ? atomicAdd(&bcnt[t * BSTR],         h[t])       : 0;
    base[t + 256] = h[t + 256] ? atomicAdd(&bcnt[(t + 256) * BSTR], h[t + 256]) : 0;
    __syncthreads();
    h[t] = 0; h[t + 256] = 0;
    __syncthreads();
    #pragma unroll
    for (int i = 0; i < EPT; ++i) {
        if (dv[i] >= 0) {
            int bkt = dv[i] >> NBSH;
            int pos = base[bkt] + atomicAdd(&h[bkt], 1);
            if (pos < CAPB)
                ebuf[(size_t)bkt * REGS + pos] =
                    (unsigned)sv[i] | ((unsigned)(dv[i] & (NPB - 1)) << 17);
        }
    }
}

// ---- K2: per-bucket CSR build IN PLACE (LDS-staged, LDS deg hist) ----
// Stages the bucket's packed edges in LDS (uint4), LDS-histograms degrees,
// then rewrites the same global region as [self][edges][sentinels pad x4].
// Writes dinv.
__global__ __launch_bounds__(256) void csr_kernel(const int* __restrict__ bcnt,
                                                  unsigned* __restrict__ buf,
                                                  int* __restrict__ begs,
                                                  int* __restrict__ lens,
                                                  float* __restrict__ dinv, int n) {
    __shared__ unsigned eb[CAPB];   // 14 KB
    __shared__ int cnt[256];
    __shared__ int tmp[256];
    int t = threadIdx.x, b = blockIdx.x;
    int ecnt = bcnt[b * BSTR]; if (ecnt > CAPB) ecnt = CAPB;
    size_t rb = (size_t)b * REGS;

    // stage packed edges to LDS, 16B vectors (region is 16B-aligned)
    const uint4* bufv = (const uint4*)(buf + rb);
    uint4* ebv = (uint4*)eb;
    int nv = (ecnt + 3) >> 2;
    for (int i = t; i < nv; i += 256) ebv[i] = bufv[i];
    cnt[t] = 0;
    __syncthreads();                                 // fences staging + cnt init
    for (int i = t; i < ecnt; i += 256) atomicAdd(&cnt[eb[i] >> 17], 1);
    __syncthreads();

    int nid = (b << NBSH) + t;
    int deg = cnt[t];
    int slots = (nid < n) ? ((deg + 4) & ~3) : 0;    // >= deg+1, multiple of 4
    tmp[t] = slots;
    __syncthreads();
    int s = slots;
    for (int o = 1; o < 256; o <<= 1) {
        int y = (t >= o) ? tmp[t - o] : 0;
        __syncthreads();
        tmp[t] += y;
        __syncthreads();
    }
    int excl = tmp[t] - s;
    int beg = (int)rb + excl;
    if (nid < n) {
        begs[nid] = beg;
        lens[nid] = slots;
        dinv[nid] = rsqrtf((float)(deg + 1));
        buf[beg] = (unsigned)nid;                              // self-loop
        for (int k = deg + 1; k < slots; ++k) buf[beg + k] = (unsigned)n;  // sentinels
    }
    cnt[t] = excl + 1;                                         // cursor past self
    __syncthreads();
    for (int i = t; i < ecnt; i += 256) {
        unsigned v = eb[i];
        int pos = atomicAdd(&cnt[v >> 17], 1);
        buf[rb + pos] = v & 0x1ffffu;
    }
}

// ---- K3: xs[row] = bf16(x[row] * dinv[row]) packed 2/dword; row n = zeros ----
// Fat grid (12501 blocks), pure BW.
__global__ __launch_bounds__(256) void xsprep_kernel(const float* __restrict__ x,
                                                     const float* __restrict__ dinv,
                                                     unsigned* __restrict__ xs, int n) {
    int i = blockIdx.x * blockDim.x + threadIdx.x;
    int total = (n + 1) * 32;
    if (i >= total) return;
    int row = i >> 5, col = i & 31;
    unsigned v = 0;
    if (row < n) {
        float di = dinv[row];
        float f0 = x[(size_t)row * DFEAT + 2 * col] * di;
        float f1 = x[(size_t)row * DFEAT + 2 * col + 1] * di;
        unsigned u0 = __float_as_uint(f0); u0 = (u0 + 0x7fffu + ((u0 >> 16) & 1u)) >> 16;
        unsigned u1 = __float_as_uint(f1); u1 = (u1 + 0x7fffu + ((u1 >> 16) & 1u)) >> 16;
        v = (u0 & 0xffffu) | (u1 << 16);
    }
    xs[i] = v;
}

// ---- Persistent fused DUAL-NODE gather -> shared GEMM(+bias) -> expmap0 -> proj ----
// (UNCHANGED)
__global__ __launch_bounds__(256) void agg_kernel(const int* __restrict__ begs,
                                                  const int* __restrict__ lens,
                                                  const int* __restrict__ srcs,
                                                  const float* __restrict__ dinv,
                                                  const uint2* __restrict__ xs2,
                                                  const float* __restrict__ W,
                                                  const float* __restrict__ b,
                                                  float* __restrict__ out,
                                                  int n, int noctets) {
    __shared__ float Wl[DFEAT * DFEAT];   // 16 KB
    __shared__ float xl[8][DFEAT];        // 2 KB
    int t = threadIdx.x;
    #pragma unroll
    for (int i = 0; i < 16; ++i) Wl[i * 256 + t] = W[i * 256 + t];
    __syncthreads();   // the ONLY barrier

    int r = t >> 6, lane = t & 63;
    int g = lane >> 4;        // edge group (0..3)
    int q = lane & 15;        // uint2 column -> features 4q..4q+3
    float bias = b[lane];

    for (int oct = blockIdx.x; oct < noctets; oct += gridDim.x) {
        int na = oct * 8 + r;
        int nb_ = na + 4;
        bool va = na < n, vb = nb_ < n;
        if (!va) continue;

        int beg0 = begs[na],  end0 = beg0 + lens[na];
        int beg1 = 0, end1 = 0;
        if (vb) { beg1 = begs[nb_]; end1 = beg1 + lens[nb_]; }

        float a0 = 0, a1 = 0, a2 = 0, a3 = 0;
        float b0 = 0, b1 = 0, b2 = 0, b3 = 0;
        int base0 = beg0, base1 = beg1;
        while (base0 < end0 || base1 < end1) {
            int m0 = end0 - base0; m0 = m0 < 0 ? 0 : (m0 > 64 ? 64 : m0);
            int m1 = end1 - base1; m1 = m1 < 0 ? 0 : (m1 > 64 ? 64 : m1);
            int idx0 = 0, idx1 = 0;
            if (lane < m0) idx0 = srcs[base0 + lane];
            if (lane < m1) idx1 = srcs[base1 + lane];
            int q0 = m0 >> 2, q1 = m1 >> 2;
            int qc = q0 < q1 ? q0 : q1;
            #pragma unroll 4
            for (int j = 0; j < qc; ++j) {
                int sv0 = __shfl(idx0, 4 * j + g, 64);
                int sv1 = __shfl(idx1, 4 * j + g, 64);
                uint2 d0 = xs2[(unsigned)sv0 * 16 + q];
                uint2 d1 = xs2[(unsigned)sv1 * 16 + q];
                a0 += __uint_as_float(d0.x << 16);
                a1 += __uint_as_float(d0.x & 0xffff0000u);
                a2 += __uint_as_float(d0.y << 16);
                a3 += __uint_as_float(d0.y & 0xffff0000u);
                b0 += __uint_as_float(d1.x << 16);
                b1 += __uint_as_float(d1.x & 0xffff0000u);
                b2 += __uint_as_float(d1.y << 16);
                b3 += __uint_as_float(d1.y & 0xffff0000u);
            }
            #pragma unroll 4
            for (int j = qc; j < q0; ++j) {
                int sv0 = __shfl(idx0, 4 * j + g, 64);
                uint2 d0 = xs2[(unsigned)sv0 * 16 + q];
                a0 += __uint_as_float(d0.x << 16);
                a1 += __uint_as_float(d0.x & 0xffff0000u);
                a2 += __uint_as_float(d0.y << 16);
                a3 += __uint_as_float(d0.y & 0xffff0000u);
            }
            #pragma unroll 4
            for (int j = qc; j < q1; ++j) {
                int sv1 = __shfl(idx1, 4 * j + g, 64);
                uint2 d1 = xs2[(unsigned)sv1 * 16 + q];
                b0 += __uint_as_float(d1.x << 16);
                b1 += __uint_as_float(d1.x & 0xffff0000u);
                b2 += __uint_as_float(d1.y << 16);
                b3 += __uint_as_float(d1.y & 0xffff0000u);
            }
            base0 += 64; base1 += 64;
        }
        #pragma unroll
        for (int off = 16; off < 64; off <<= 1) {
            a0 += __shfl_xor(a0, off, 64);
            a1 += __shfl_xor(a1, off, 64);
            a2 += __shfl_xor(a2, off, 64);
            a3 += __shfl_xor(a3, off, 64);
            b0 += __shfl_xor(b0, off, 64);
            b1 += __shfl_xor(b1, off, 64);
            b2 += __shfl_xor(b2, off, 64);
            b3 += __shfl_xor(b3, off, 64);
        }
        if (g == 0) {
            float dia = dinv[na];
            xl[r][4 * q + 0] = a0 * dia;
            xl[r][4 * q + 1] = a1 * dia;
            xl[r][4 * q + 2] = a2 * dia;
            xl[r][4 * q + 3] = a3 * dia;
            if (vb) {
                float dib = dinv[nb_];
                xl[r + 4][4 * q + 0] = b0 * dib;
                xl[r + 4][4 * q + 1] = b1 * dib;
                xl[r + 4][4 * q + 2] = b2 * dib;
                xl[r + 4][4 * q + 3] = b3 * dib;
            }
        }
        // wave-synchronous LDS: same wave wrote xl rows r / r+4, same wave reads.

        float oa0 = bias, oa1 = 0.0f, ob0 = bias, ob1 = 0.0f;
        #pragma unroll
        for (int k = 0; k < DFEAT; k += 2) {
            float w0 = Wl[k * DFEAT + lane];
            float w1 = Wl[(k + 1) * DFEAT + lane];
            oa0 = fmaf(xl[r][k],     w0, oa0);
            oa1 = fmaf(xl[r][k + 1], w1, oa1);
            ob0 = fmaf(xl[r + 4][k],     w0, ob0);
            ob1 = fmaf(xl[r + 4][k + 1], w1, ob1);
        }
        float oa = oa0 + oa1;
        float ob = ob0 + ob1;

        float ssa = oa * oa, ssb = ob * ob;
        #pragma unroll
        for (int off = 32; off > 0; off >>= 1) {
            ssa += __shfl_xor(ssa, off, 64);
            ssb += __shfl_xor(ssb, off, 64);
        }
        float norma = fmaxf(sqrtf(ssa), 1e-15f);
        float sca = fminf(tanhf(norma), 1.0f - 4e-3f) / norma;
        out[(long long)na * DFEAT + lane] = oa * sca;
        if (vb) {
            float normb = fmaxf(sqrtf(ssb), 1e-15f);
            float scb = fminf(tanhf(normb), 1.0f - 4e-3f) / normb;
            out[(long long)nb_ * DFEAT + lane] = ob * scb;
        }
    }
}

// ---------------- launch ----------------

extern "C" void kernel_launch(void* const* d_in, const int* in_sizes, int n_in,
                              void* d_out, int out_size, void* d_ws, size_t ws_size,
                              hipStream_t stream) {
    const float* x = (const float*)d_in[0];
    const float* W = (const float*)d_in[1];
    const float* b = (const float*)d_in[2];
    const int* ei  = (const int*)d_in[3];

    int n = in_sizes[0] / DFEAT;           // 100000
    int E = in_sizes[3] / 2;               // 1200000
    int NBUCK = (n + NPB - 1) / NPB;       // 391
    int nblk = (E + EPB - 1) / EPB;        // 293
    int noctets = (n + 7) / 8;             // 12500

    // workspace layout, ~21.3 MB total
    int* bcnt = (int*)d_ws;                               // 512*BSTR (zeroed, padded)
    unsigned* buf = (unsigned*)(bcnt + 512 * BSTR);       // NBUCK*REGS (~7.2 MB), 16B-aligned
    int* begs = (int*)(buf + (size_t)NBUCK * REGS);       // n
    int* lens = begs + n;                                 // n
    float* dinv = (float*)(lens + n);                     // n
    size_t xsoff = (size_t)(((int*)dinv + n) - (int*)d_ws);
    xsoff = (xsoff + 31) & ~(size_t)31;                   // 128B-align
    unsigned* xs = (unsigned*)d_ws + xsoff;               // (n+1)*32

    float* out = (float*)d_out;

    int aggblocks = 2048;                  // 8 blocks/CU (LDS 18K)
    if (aggblocks > noctets) aggblocks = noctets;
    int xsblocks = ((n + 1) * 32 + 255) / 256;            // 12501

    hipMemsetAsync(bcnt, 0, 512 * BSTR * sizeof(int), stream);
    part_kernel  <<<nblk, 256, 0, stream>>>(ei, bcnt, buf, E);
    csr_kernel   <<<NBUCK, 256, 0, stream>>>(bcnt, buf, begs, lens, dinv, n);
    xsprep_kernel<<<xsblocks, 256, 0, stream>>>(x, dinv, xs, n);
    agg_kernel   <<<aggblocks, 256, 0, stream>>>(begs, lens, (const int*)buf, dinv,
                                                 (const uint2*)xs, W, b, out, n, noctets);
}